// Round 3
// baseline (1028.176 us; speedup 1.0000x reference)
//
#include <hip/hip_runtime.h>
#include <stdint.h>

#define DIM   2048
#define NEXP  8
#define EDIM  1024
#define NTOK  8192   // B*S = 4*2048

using bf16x8 = __attribute__((ext_vector_type(8))) short;
using f32x4  = __attribute__((ext_vector_type(4))) float;
using u16x2  = __attribute__((ext_vector_type(2))) unsigned short;

typedef __attribute__((address_space(3))) void lds_void_t;
typedef const __attribute__((address_space(1))) void gbl_void_t;

__device__ static inline void load_lds16(const void* g, void* l) {
    __builtin_amdgcn_global_load_lds((gbl_void_t*)g, (lds_void_t*)l, 16, 0, 0);
}

// fp32 -> bf16 bits, round-to-nearest-even
__device__ static inline unsigned short f2b(float x) {
    union { float f; unsigned u; } v; v.f = x;
    unsigned r = v.u + 0x7fffu + ((v.u >> 16) & 1u);
    return (unsigned short)(r >> 16);
}

// tanh-approx gelu (matches jax.nn.gelu approximate=True)
__device__ static inline float gelu_f(float x) {
    float u = 0.7978845608028654f * x * (1.0f + 0.044715f * x * x);
    u = fminf(fmaxf(u, -15.0f), 15.0f);
    float e = __expf(2.0f * u);
    float th = (e - 1.0f) / (e + 1.0f);
    return 0.5f * x * (1.0f + th);
}

// ---------------------------------------------------------------------------
// Transpose + cast fp32 [R,C] row-major -> bf16 [C,R] row-major. 64x64 tiles.
// ---------------------------------------------------------------------------
__global__ __launch_bounds__(256)
void transpose_cast(const float* __restrict__ in, unsigned short* __restrict__ out,
                    int R, int C) {
    __shared__ float tile[64][65];
    const size_t slab = (size_t)blockIdx.z * R * C;
    in  += slab;
    out += slab;
    const int r0 = blockIdx.y * 64;
    const int c0 = blockIdx.x * 64;
    const int tx = threadIdx.x & 63;
    const int tw = threadIdx.x >> 6;
    #pragma unroll
    for (int i = 0; i < 16; ++i)
        tile[tw * 16 + i][tx] = in[(size_t)(r0 + tw * 16 + i) * C + c0 + tx];
    __syncthreads();
    const int rp = (threadIdx.x & 31) * 2;   // r-pair base (lane covers 2 rows)
    const int cy = threadIdx.x >> 5;         // 0..7
    #pragma unroll
    for (int j = 0; j < 8; ++j) {
        const int c = cy + j * 8;
        u16x2 v;
        v.x = f2b(tile[rp][c]);
        v.y = f2b(tile[rp + 1][c]);
        *(u16x2*)&out[(size_t)(c0 + c) * R + r0 + rp] = v;
    }
}

// ---------------------------------------------------------------------------
// Router + x cast: one block per token. float4 Wr loads.
// ---------------------------------------------------------------------------
__global__ __launch_bounds__(256)
void router_convert(const float* __restrict__ x, const float* __restrict__ Wr,
                    const float* __restrict__ br, unsigned short* __restrict__ xb,
                    float* __restrict__ probs) {
    const int t   = blockIdx.x;
    const int tid = threadIdx.x;
    const float* xr = x + (size_t)t * DIM;
    const float4* Wr4 = (const float4*)Wr;   // [DIM][2] float4
    float s[NEXP];
    #pragma unroll
    for (int e = 0; e < NEXP; ++e) s[e] = 0.f;
    for (int j = tid; j < DIM; j += 256) {
        float v = xr[j];
        xb[(size_t)t * DIM + j] = f2b(v);
        const float4 w0 = Wr4[j * 2];
        const float4 w1 = Wr4[j * 2 + 1];
        s[0] += v * w0.x; s[1] += v * w0.y; s[2] += v * w0.z; s[3] += v * w0.w;
        s[4] += v * w1.x; s[5] += v * w1.y; s[6] += v * w1.z; s[7] += v * w1.w;
    }
    #pragma unroll
    for (int e = 0; e < NEXP; ++e)
        #pragma unroll
        for (int off = 32; off > 0; off >>= 1) s[e] += __shfl_down(s[e], off);
    __shared__ float part[4][NEXP];
    const int wave = tid >> 6, lane = tid & 63;
    if (lane == 0) {
        #pragma unroll
        for (int e = 0; e < NEXP; ++e) part[wave][e] = s[e];
    }
    __syncthreads();
    if (tid == 0) {
        float l[NEXP], mx = -1e30f;
        #pragma unroll
        for (int e = 0; e < NEXP; ++e) {
            l[e] = part[0][e] + part[1][e] + part[2][e] + part[3][e] + br[e];
            mx = fmaxf(mx, l[e]);
        }
        float sum = 0.f;
        #pragma unroll
        for (int e = 0; e < NEXP; ++e) { l[e] = __expf(l[e] - mx); sum += l[e]; }
        const float inv = 1.f / sum;
        #pragma unroll
        for (int e = 0; e < NEXP; ++e) probs[t * NEXP + e] = l[e] * inv;
    }
}

// ---------------------------------------------------------------------------
// bf16 GEMM: C[M,N] = A[M,K] * Bt[N,K]^T
// 128x128 tile, BK=32, 4 waves (2x2), 4x4 of 16x16x32 MFMA per wave.
// R3: single-barrier double-buffered K-loop — prefetch tile k+1 via
// global_load_lds BEFORE the MFMA phase of tile k; the compiler-emitted
// vmcnt(0) drain at the one barrier/iter then waits on ~1-MFMA-phase-old
// loads. Staging uses the LINEAR chunk map (R1) — the R2 XOR swizzle broke
// the DMA's 64B-contiguity and cost 11% (bank conflicts are hidden; keep them).
// GROUP_M=8 supertile swizzle for L2 locality.
// ---------------------------------------------------------------------------
template <int MODE>
__global__ __launch_bounds__(256, 4)
void gemm_bt(const unsigned short* __restrict__ A,
             const unsigned short* __restrict__ Bt,
             int M, int N, int K,
             const float* __restrict__ probs,
             const float* __restrict__ bias,
             const float* __restrict__ xres,
             void* __restrict__ Cout)
{
    __shared__ unsigned short As[2][128 * 32];
    __shared__ unsigned short Bs[2][128 * 32];
    const int tid  = threadIdx.x;
    const int wave = tid >> 6;
    const int lane = tid & 63;
    const int wi = wave >> 1, wj = wave & 1;

    // GROUP_M=8 supertile swizzle: col-major within an 8-row stripe.
    const int bid  = blockIdx.y * gridDim.x + blockIdx.x;
    const int nig  = 8 * gridDim.x;
    const int grp  = bid / nig;
    const int rem  = bid - grp * nig;
    const int row0 = (grp * 8 + (rem & 7)) * 128;
    const int col0 = (rem >> 3) * 128;

    // staging: slot g holds chunk (row=g>>2, kc=g&3) — linear, DMA-contiguous
    const int g0 = wave * 128 + lane;
    const int g1 = g0 + 64;
    const int ar0 = g0 >> 2, ac0 = (g0 & 3) * 8;
    const int ar1 = g1 >> 2, ac1 = (g1 & 3) * 8;

    const unsigned short* pA0 = A  + (size_t)(row0 + ar0) * K + ac0;
    const unsigned short* pA1 = A  + (size_t)(row0 + ar1) * K + ac1;
    const unsigned short* pB0 = Bt + (size_t)(col0 + ar0) * K + ac0;
    const unsigned short* pB1 = Bt + (size_t)(col0 + ar1) * K + ac1;

    const int m = lane & 15;   // row (A) / col (B) within 16
    const int q = lane >> 4;   // k-chunk quad
    const int qo = q * 8;      // k offset in halfwords

    f32x4 acc[4][4];
    #pragma unroll
    for (int i = 0; i < 4; ++i)
        #pragma unroll
        for (int j = 0; j < 4; ++j)
            acc[i][j] = (f32x4){0.f, 0.f, 0.f, 0.f};

    // prologue: stage tile 0 into buffer 0
    load_lds16(pA0, &As[0][g0 * 8]);
    load_lds16(pA1, &As[0][g1 * 8]);
    load_lds16(pB0, &Bs[0][g0 * 8]);
    load_lds16(pB1, &Bs[0][g1 * 8]);

    const int niter = K >> 5;
    for (int it = 0; it < niter; ++it) {
        const int cur = it & 1;
        const int nxt = cur ^ 1;
        __syncthreads();   // drains this wave's DMAs (vmcnt0) -> tile[cur] valid everywhere
        if (it + 1 < niter) {
            const int k0 = (it + 1) << 5;
            load_lds16(pA0 + k0, &As[nxt][g0 * 8]);
            load_lds16(pA1 + k0, &As[nxt][g1 * 8]);
            load_lds16(pB0 + k0, &Bs[nxt][g0 * 8]);
            load_lds16(pB1 + k0, &Bs[nxt][g1 * 8]);
        }
        bf16x8 a[4], b[4];
        #pragma unroll
        for (int t = 0; t < 4; ++t)
            a[t] = *(const bf16x8*)&As[cur][(wi * 64 + t * 16 + m) * 32 + qo];
        #pragma unroll
        for (int t = 0; t < 4; ++t)
            b[t] = *(const bf16x8*)&Bs[cur][(wj * 64 + t * 16 + m) * 32 + qo];
        #pragma unroll
        for (int i = 0; i < 4; ++i)
            #pragma unroll
            for (int j = 0; j < 4; ++j)
                acc[i][j] = __builtin_amdgcn_mfma_f32_16x16x32_bf16(a[i], b[j], acc[i][j], 0, 0, 0);
        // no second barrier: buf[nxt] writes were issued only after the barrier
        // above, and every wave's reads of buf[nxt] (iter it-1) completed
        // before that same barrier.
    }

    // C/D layout (m89-verified): col = lane&15, row = (lane>>4)*4 + reg
    if (MODE == 1) {
        unsigned short* H = (unsigned short*)Cout;
        const int e = col0 >> 10;   // 128-wide tile never crosses an expert boundary
        #pragma unroll
        for (int i = 0; i < 4; ++i) {
            #pragma unroll
            for (int r = 0; r < 4; ++r) {
                const int rowg = row0 + wi * 64 + i * 16 + q * 4 + r;
                const float p = probs[rowg * NEXP + e];
                #pragma unroll
                for (int j = 0; j < 4; ++j) {
                    const int colg = col0 + wj * 64 + j * 16 + m;
                    float v = acc[i][j][r] + bias[colg];   // bu flat index = e*1024+f = colg
                    H[(size_t)rowg * N + colg] = f2b(gelu_f(v) * p);
                }
            }
        }
    } else {
        float* O = (float*)Cout;
        #pragma unroll
        for (int i = 0; i < 4; ++i) {
            #pragma unroll
            for (int r = 0; r < 4; ++r) {
                const int rowg = row0 + wi * 64 + i * 16 + q * 4 + r;
                float p[NEXP];
                #pragma unroll
                for (int e = 0; e < NEXP; ++e) p[e] = probs[rowg * NEXP + e];
                #pragma unroll
                for (int j = 0; j < 4; ++j) {
                    const int colg = col0 + wj * 64 + j * 16 + m;
                    float v = acc[i][j][r];
                    #pragma unroll
                    for (int e = 0; e < NEXP; ++e) v += p[e] * bias[e * DIM + colg];
                    v += xres[(size_t)rowg * DIM + colg];
                    O[(size_t)rowg * N + colg] = v;
                }
            }
        }
    }
}

// ---------------------------------------------------------------------------
// Workspace layout (bytes):
//   xb    bf16 [8192,2048]        @ 0          (33554432)
//   WuT   bf16 [8][1024,2048]     @ 33554432   (33554432)
//   WdT   bf16 [2048,8192]        @ 67108864   (33554432)
//   probs fp32 [8192,8]           @ 100663296  (262144)
//   h     bf16 [8192,8192]        @ 100925440  (134217728)
// ---------------------------------------------------------------------------
extern "C" void kernel_launch(void* const* d_in, const int* in_sizes, int n_in,
                              void* d_out, int out_size, void* d_ws, size_t ws_size,
                              hipStream_t stream) {
    const float* x  = (const float*)d_in[0];
    const float* Wr = (const float*)d_in[1];
    const float* br = (const float*)d_in[2];
    const float* Wu = (const float*)d_in[3];
    const float* bu = (const float*)d_in[4];
    const float* Wd = (const float*)d_in[5];
    const float* bd = (const float*)d_in[6];
    float* out = (float*)d_out;

    char* ws = (char*)d_ws;
    unsigned short* xb    = (unsigned short*)(ws);
    unsigned short* WuT   = (unsigned short*)(ws + 33554432);
    unsigned short* WdT   = (unsigned short*)(ws + 67108864);
    float*          probs = (float*)(ws + 100663296);
    unsigned short* h     = (unsigned short*)(ws + 100925440);

    // Wu [e][2048][1024] -> WuT [e][1024][2048]
    transpose_cast<<<dim3(EDIM / 64, DIM / 64, NEXP), 256, 0, stream>>>(Wu, WuT, DIM, EDIM);
    // Wd [8192][2048] -> WdT [2048][8192]
    transpose_cast<<<dim3(DIM / 64, (NEXP * EDIM) / 64, 1), 256, 0, stream>>>(Wd, WdT, NEXP * EDIM, DIM);
    // router softmax + x -> bf16
    router_convert<<<NTOK, 256, 0, stream>>>(x, Wr, br, xb, probs);
    // GEMM1: h = bf16( probs_e * gelu(x @ Wu + bu) )   M=8192 N=8192 K=2048
    gemm_bt<1><<<dim3((NEXP * EDIM) / 128, NTOK / 128), 256, 0, stream>>>(
        xb, WuT, NTOK, NEXP * EDIM, DIM, probs, bu, nullptr, h);
    // GEMM2: out = h @ Wd_concat + probs@bd + x        M=8192 N=2048 K=8192
    gemm_bt<2><<<dim3(DIM / 128, NTOK / 128), 256, 0, stream>>>(
        h, WdT, NTOK, DIM, NEXP * EDIM, probs, bd, x, out);
}

// Round 4
// 798.802 us; speedup vs baseline: 1.2871x; 1.2871x over previous
//
#include <hip/hip_runtime.h>
#include <stdint.h>

#define DIM   2048
#define NEXP  8
#define EDIM  1024
#define NTOK  8192   // B*S = 4*2048

using bf16x8 = __attribute__((ext_vector_type(8))) short;
using f32x4  = __attribute__((ext_vector_type(4))) float;
using u16x2  = __attribute__((ext_vector_type(2))) unsigned short;

typedef __attribute__((address_space(3))) void lds_void_t;
typedef const __attribute__((address_space(1))) void gbl_void_t;

__device__ static inline void load_lds16(const void* g, void* l) {
    __builtin_amdgcn_global_load_lds((gbl_void_t*)g, (lds_void_t*)l, 16, 0, 0);
}

// fp32 -> bf16 bits, round-to-nearest-even
__device__ static inline unsigned short f2b(float x) {
    union { float f; unsigned u; } v; v.f = x;
    unsigned r = v.u + 0x7fffu + ((v.u >> 16) & 1u);
    return (unsigned short)(r >> 16);
}

// tanh-approx gelu (matches jax.nn.gelu approximate=True)
__device__ static inline float gelu_f(float x) {
    float u = 0.7978845608028654f * x * (1.0f + 0.044715f * x * x);
    u = fminf(fmaxf(u, -15.0f), 15.0f);
    float e = __expf(2.0f * u);
    float th = (e - 1.0f) / (e + 1.0f);
    return 0.5f * x * (1.0f + th);
}

// ---------------------------------------------------------------------------
// Transpose + cast fp32 [R,C] row-major -> bf16 [C,R] row-major. 64x64 tiles.
// ---------------------------------------------------------------------------
__global__ __launch_bounds__(256)
void transpose_cast(const float* __restrict__ in, unsigned short* __restrict__ out,
                    int R, int C) {
    __shared__ float tile[64][65];
    const size_t slab = (size_t)blockIdx.z * R * C;
    in  += slab;
    out += slab;
    const int r0 = blockIdx.y * 64;
    const int c0 = blockIdx.x * 64;
    const int tx = threadIdx.x & 63;
    const int tw = threadIdx.x >> 6;
    #pragma unroll
    for (int i = 0; i < 16; ++i)
        tile[tw * 16 + i][tx] = in[(size_t)(r0 + tw * 16 + i) * C + c0 + tx];
    __syncthreads();
    const int rp = (threadIdx.x & 31) * 2;   // r-pair base (lane covers 2 rows)
    const int cy = threadIdx.x >> 5;         // 0..7
    #pragma unroll
    for (int j = 0; j < 8; ++j) {
        const int c = cy + j * 8;
        u16x2 v;
        v.x = f2b(tile[rp][c]);
        v.y = f2b(tile[rp + 1][c]);
        *(u16x2*)&out[(size_t)(c0 + c) * R + r0 + rp] = v;
    }
}

// ---------------------------------------------------------------------------
// Router + x cast: one block per token. float4 Wr loads.
// ---------------------------------------------------------------------------
__global__ __launch_bounds__(256)
void router_convert(const float* __restrict__ x, const float* __restrict__ Wr,
                    const float* __restrict__ br, unsigned short* __restrict__ xb,
                    float* __restrict__ probs) {
    const int t   = blockIdx.x;
    const int tid = threadIdx.x;
    const float* xr = x + (size_t)t * DIM;
    const float4* Wr4 = (const float4*)Wr;   // [DIM][2] float4
    float s[NEXP];
    #pragma unroll
    for (int e = 0; e < NEXP; ++e) s[e] = 0.f;
    for (int j = tid; j < DIM; j += 256) {
        float v = xr[j];
        xb[(size_t)t * DIM + j] = f2b(v);
        const float4 w0 = Wr4[j * 2];
        const float4 w1 = Wr4[j * 2 + 1];
        s[0] += v * w0.x; s[1] += v * w0.y; s[2] += v * w0.z; s[3] += v * w0.w;
        s[4] += v * w1.x; s[5] += v * w1.y; s[6] += v * w1.z; s[7] += v * w1.w;
    }
    #pragma unroll
    for (int e = 0; e < NEXP; ++e)
        #pragma unroll
        for (int off = 32; off > 0; off >>= 1) s[e] += __shfl_down(s[e], off);
    __shared__ float part[4][NEXP];
    const int wave = tid >> 6, lane = tid & 63;
    if (lane == 0) {
        #pragma unroll
        for (int e = 0; e < NEXP; ++e) part[wave][e] = s[e];
    }
    __syncthreads();
    if (tid == 0) {
        float l[NEXP], mx = -1e30f;
        #pragma unroll
        for (int e = 0; e < NEXP; ++e) {
            l[e] = part[0][e] + part[1][e] + part[2][e] + part[3][e] + br[e];
            mx = fmaxf(mx, l[e]);
        }
        float sum = 0.f;
        #pragma unroll
        for (int e = 0; e < NEXP; ++e) { l[e] = __expf(l[e] - mx); sum += l[e]; }
        const float inv = 1.f / sum;
        #pragma unroll
        for (int e = 0; e < NEXP; ++e) probs[t * NEXP + e] = l[e] * inv;
    }
}

// ---------------------------------------------------------------------------
// bf16 GEMM: C[M,N] = A[M,K] * Bt[N,K]^T
// R4 = exact R1 structure (two-barrier K-loop, row-major block order,
// lb(256,2)) with ONE change: BK=64 — halves barrier count, amortizing the
// per-barrier vmcnt(0) drain over 32 MFMA/wave instead of 16.
// R2/R3 lesson: GROUP_M swizzle / lb(256,4) cost 11%; staging-side XOR chunk
// permutation is free. With BK=64 the LDS row stride is 128 B (all rows
// bank-aligned -> 16-way read conflicts, NOT hidden), so the slot->chunk map
// XORs the k-chunk with (row&7): fragment ds_read_b128 becomes 2-way (free,
// m136) and the DMA still sees contiguous permuted 128 B row runs.
// LDS slot g (of 1024/matrix) holds chunk (row=g>>3, kc=(g&7)^(row&7)).
// ---------------------------------------------------------------------------
template <int MODE>
__global__ __launch_bounds__(256, 2)
void gemm_bt(const unsigned short* __restrict__ A,
             const unsigned short* __restrict__ Bt,
             int M, int N, int K,
             const float* __restrict__ probs,
             const float* __restrict__ bias,
             const float* __restrict__ xres,
             void* __restrict__ Cout)
{
    __shared__ unsigned short As[128 * 64];
    __shared__ unsigned short Bs[128 * 64];
    const int tid  = threadIdx.x;
    const int wave = tid >> 6;
    const int lane = tid & 63;
    const int wi = wave >> 1, wj = wave & 1;
    const int row0 = blockIdx.y * 128;
    const int col0 = blockIdx.x * 128;

    // staging: thread handles slots g = s*256 + tid, s=0..3 (per matrix)
    const unsigned short* pA[4];
    const unsigned short* pB[4];
    unsigned short* dA[4];
    unsigned short* dB[4];
    #pragma unroll
    for (int s = 0; s < 4; ++s) {
        const int g  = s * 256 + tid;
        const int r  = g >> 3;
        const int kc = (g & 7) ^ (r & 7);
        pA[s] = A  + (size_t)(row0 + r) * K + kc * 8;
        pB[s] = Bt + (size_t)(col0 + r) * K + kc * 8;
        dA[s] = &As[g * 8];
        dB[s] = &Bs[g * 8];
    }

    const int m = lane & 15;   // row (A) / col (B) within 16
    const int q = lane >> 4;   // k-chunk quad within a 32-K step
    const int xsw = m & 7;     // row&7 for every row this lane reads
    // fragment LDS halfword offsets: row base + swizzled chunk
    int aoff[4], boff[4], ko[2];
    #pragma unroll
    for (int t = 0; t < 4; ++t) {
        aoff[t] = (wi * 64 + t * 16 + m) * 64;
        boff[t] = (wj * 64 + t * 16 + m) * 64;
    }
    #pragma unroll
    for (int u = 0; u < 2; ++u)
        ko[u] = ((u * 4 + q) ^ xsw) * 8;

    f32x4 acc[4][4];
    #pragma unroll
    for (int i = 0; i < 4; ++i)
        #pragma unroll
        for (int j = 0; j < 4; ++j)
            acc[i][j] = (f32x4){0.f, 0.f, 0.f, 0.f};

    for (int k0 = 0; k0 < K; k0 += 64) {
        #pragma unroll
        for (int s = 0; s < 4; ++s) load_lds16(pA[s], dA[s]);
        #pragma unroll
        for (int s = 0; s < 4; ++s) load_lds16(pB[s], dB[s]);
        #pragma unroll
        for (int s = 0; s < 4; ++s) { pA[s] += 64; pB[s] += 64; }
        __syncthreads();   // vmcnt(0) drain: tile valid for all waves
        #pragma unroll
        for (int u = 0; u < 2; ++u) {
            bf16x8 a[4], b[4];
            #pragma unroll
            for (int t = 0; t < 4; ++t)
                a[t] = *(const bf16x8*)&As[aoff[t] + ko[u]];
            #pragma unroll
            for (int t = 0; t < 4; ++t)
                b[t] = *(const bf16x8*)&Bs[boff[t] + ko[u]];
            #pragma unroll
            for (int i = 0; i < 4; ++i)
                #pragma unroll
                for (int j = 0; j < 4; ++j)
                    acc[i][j] = __builtin_amdgcn_mfma_f32_16x16x32_bf16(a[i], b[j], acc[i][j], 0, 0, 0);
        }
        __syncthreads();
    }

    // C/D layout (m89-verified): col = lane&15, row = (lane>>4)*4 + reg
    if (MODE == 1) {
        unsigned short* H = (unsigned short*)Cout;
        const int e = col0 >> 10;   // 128-wide tile never crosses an expert boundary
        #pragma unroll
        for (int i = 0; i < 4; ++i) {
            #pragma unroll
            for (int r = 0; r < 4; ++r) {
                const int rowg = row0 + wi * 64 + i * 16 + q * 4 + r;
                const float p = probs[rowg * NEXP + e];
                #pragma unroll
                for (int j = 0; j < 4; ++j) {
                    const int colg = col0 + wj * 64 + j * 16 + m;
                    float v = acc[i][j][r] + bias[colg];   // bu flat index = e*1024+f = colg
                    H[(size_t)rowg * N + colg] = f2b(gelu_f(v) * p);
                }
            }
        }
    } else {
        float* O = (float*)Cout;
        #pragma unroll
        for (int i = 0; i < 4; ++i) {
            #pragma unroll
            for (int r = 0; r < 4; ++r) {
                const int rowg = row0 + wi * 64 + i * 16 + q * 4 + r;
                float p[NEXP];
                #pragma unroll
                for (int e = 0; e < NEXP; ++e) p[e] = probs[rowg * NEXP + e];
                #pragma unroll
                for (int j = 0; j < 4; ++j) {
                    const int colg = col0 + wj * 64 + j * 16 + m;
                    float v = acc[i][j][r];
                    #pragma unroll
                    for (int e = 0; e < NEXP; ++e) v += p[e] * bias[e * DIM + colg];
                    v += xres[(size_t)rowg * DIM + colg];
                    O[(size_t)rowg * N + colg] = v;
                }
            }
        }
    }
}

// ---------------------------------------------------------------------------
// Workspace layout (bytes):
//   xb    bf16 [8192,2048]        @ 0          (33554432)
//   WuT   bf16 [8][1024,2048]     @ 33554432   (33554432)
//   WdT   bf16 [2048,8192]        @ 67108864   (33554432)
//   probs fp32 [8192,8]           @ 100663296  (262144)
//   h     bf16 [8192,8192]        @ 100925440  (134217728)
// ---------------------------------------------------------------------------
extern "C" void kernel_launch(void* const* d_in, const int* in_sizes, int n_in,
                              void* d_out, int out_size, void* d_ws, size_t ws_size,
                              hipStream_t stream) {
    const float* x  = (const float*)d_in[0];
    const float* Wr = (const float*)d_in[1];
    const float* br = (const float*)d_in[2];
    const float* Wu = (const float*)d_in[3];
    const float* bu = (const float*)d_in[4];
    const float* Wd = (const float*)d_in[5];
    const float* bd = (const float*)d_in[6];
    float* out = (float*)d_out;

    char* ws = (char*)d_ws;
    unsigned short* xb    = (unsigned short*)(ws);
    unsigned short* WuT   = (unsigned short*)(ws + 33554432);
    unsigned short* WdT   = (unsigned short*)(ws + 67108864);
    float*          probs = (float*)(ws + 100663296);
    unsigned short* h     = (unsigned short*)(ws + 100925440);

    // Wu [e][2048][1024] -> WuT [e][1024][2048]
    transpose_cast<<<dim3(EDIM / 64, DIM / 64, NEXP), 256, 0, stream>>>(Wu, WuT, DIM, EDIM);
    // Wd [8192][2048] -> WdT [2048][8192]
    transpose_cast<<<dim3(DIM / 64, (NEXP * EDIM) / 64, 1), 256, 0, stream>>>(Wd, WdT, NEXP * EDIM, DIM);
    // router softmax + x -> bf16
    router_convert<<<NTOK, 256, 0, stream>>>(x, Wr, br, xb, probs);
    // GEMM1: h = bf16( probs_e * gelu(x @ Wu + bu) )   M=8192 N=8192 K=2048
    gemm_bt<1><<<dim3((NEXP * EDIM) / 128, NTOK / 128), 256, 0, stream>>>(
        xb, WuT, NTOK, NEXP * EDIM, DIM, probs, bu, nullptr, h);
    // GEMM2: out = h @ Wd_concat + probs@bd + x        M=8192 N=2048 K=8192
    gemm_bt<2><<<dim3(DIM / 128, NTOK / 128), 256, 0, stream>>>(
        h, WdT, NTOK, DIM, NEXP * EDIM, probs, bd, x, out);
}